// Round 17
// baseline (513.775 us; speedup 1.0000x reference)
//
#include <hip/hip_runtime.h>
#include <hip/hip_bf16.h>
#include <hip/hip_fp16.h>

// Nystromformer layer: b=4, n=4096, dim=512, heads=8, dim_head=64, m=256, pinv_iters=6
#define B_ 4
#define H_ 8
#define N_ 4096
#define DH_ 64
#define D_ 512
#define M_ 256
#define BH_ 32
#define NT_ 16384

typedef unsigned short u16;
using sh8 = __attribute__((ext_vector_type(8))) short;
using f4  = __attribute__((ext_vector_type(4))) float;

__device__ __forceinline__ float bf2f(u16 u){ return __uint_as_float(((unsigned)u)<<16); }
__device__ __forceinline__ u16 f2bf(float f){
  unsigned u = __float_as_uint(f);
  u += 0x7fffu + ((u>>16)&1u);
  return (u16)(u>>16);
}

// ---------------- prep: LayerNorm (blocks 0..NT_-1) + weight transpose-casts ----------------
__global__ __launch_bounds__(256) void prep_kernel(const float* __restrict__ x,
    const float* __restrict__ w, const float* __restrict__ b, u16* __restrict__ h,
    const float* __restrict__ wqkv, u16* __restrict__ wqkvT,
    const float* __restrict__ wout, u16* __restrict__ woutT){
  int t = threadIdx.x;
  if (blockIdx.x < NT_){
    int row = blockIdx.x;
    const float2* xr = (const float2*)(x + (size_t)row*D_);
    float2 v = xr[t];
    float s = v.x+v.y, ss = v.x*v.x+v.y*v.y;
    #pragma unroll
    for (int o=32;o;o>>=1){ s += __shfl_xor(s,o); ss += __shfl_xor(ss,o); }
    __shared__ float sb[4], sb2[4];
    if ((t&63)==0){ sb[t>>6]=s; sb2[t>>6]=ss; }
    __syncthreads();
    float ts  = sb[0]+sb[1]+sb[2]+sb[3];
    float tss = sb2[0]+sb2[1]+sb2[2]+sb2[3];
    float mean = ts*(1.f/D_);
    float var  = tss*(1.f/D_) - mean*mean;
    float rstd = rsqrtf(var+1e-5f);
    int c = 2*t;
    float o0 = (v.x-mean)*rstd*w[c]   + b[c];
    float o1 = (v.y-mean)*rstd*w[c+1] + b[c+1];
    u16* hr = h + (size_t)row*D_;
    hr[c] = f2bf(o0); hr[c+1] = f2bf(o1);
  } else {
    int idx = (blockIdx.x - NT_)*256 + t;
    if (idx < 512*1536){
      int k = idx/1536, n = idx - k*1536;
      wqkvT[(size_t)n*512 + k] = f2bf(wqkv[idx]);
    } else {
      int i2 = idx - 512*1536;
      if (i2 < 512*512){
        int k = i2>>9, n = i2&511;
        woutT[(size_t)n*512 + k] = f2bf(wout[i2]);
      }
    }
  }
}

// ---------------- QKV GEMM: h(16384x512) @ wqkvT(1536x512)^T, LDS-bounced epilogue ----------------
__global__ __launch_bounds__(256) void gemm_qkv(const u16* __restrict__ A,
    const u16* __restrict__ Bt, u16* __restrict__ q, u16* __restrict__ k, u16* __restrict__ v){
  __shared__ __align__(16) short sm[2*128*72];
  short* As = sm; short* Bs = sm + 128*72;
  int r0 = blockIdx.x*128, c0 = blockIdx.y*128;
  int tid = threadIdx.x, lane = tid&63, w = tid>>6;
  int wr = w>>1, wc = w&1;
  f4 acc[4][4];
  #pragma unroll
  for (int i=0;i<4;i++){
    #pragma unroll
    for (int j=0;j<4;j++) acc[i][j]=0;
  }
  for (int kt=0;kt<8;kt++){
    __syncthreads();
    #pragma unroll
    for (int i=0;i<4;i++){
      int c = i*256+tid, row = c>>3, kg = c&7;
      *(sh8*)&As[row*72+kg*8] = *(const sh8*)(A + (size_t)(r0+row)*512 + kt*64 + kg*8);
      *(sh8*)&Bs[row*72+kg*8] = *(const sh8*)(Bt + (size_t)(c0+row)*512 + kt*64 + kg*8);
    }
    __syncthreads();
    #pragma unroll
    for (int kc=0;kc<2;kc++){
      sh8 a[4], bq[4];
      #pragma unroll
      for (int fr=0;fr<4;fr++) a[fr]  = *(const sh8*)&As[(wr*64+fr*16+(lane&15))*72 + kc*32 + ((lane>>4)<<3)];
      #pragma unroll
      for (int fc=0;fc<4;fc++) bq[fc] = *(const sh8*)&Bs[(wc*64+fc*16+(lane&15))*72 + kc*32 + ((lane>>4)<<3)];
      #pragma unroll
      for (int fr=0;fr<4;fr++){
        #pragma unroll
        for (int fc=0;fc<4;fc++)
          acc[fr][fc] = __builtin_amdgcn_mfma_f32_16x16x32_bf16(a[fr], bq[fc], acc[fr][fc], 0,0,0);
      }
    }
  }
  // epilogue: bounce 64x128 f32 half-tiles through LDS, emit 16B bf16 stores
  float* tb = (float*)sm;   // 64x132 f32 = 33792B
  #pragma unroll 1
  for (int pass=0; pass<2; pass++){
    __syncthreads();
    if (wr==pass){
      #pragma unroll
      for (int fr=0;fr<4;fr++){
        #pragma unroll
        for (int fc=0;fc<4;fc++){
          #pragma unroll
          for (int j=0;j<4;j++)
            tb[(fr*16+((lane>>4)<<2)+j)*132 + wc*64+fc*16+(lane&15)] = acc[fr][fc][j];
        }
      }
    }
    __syncthreads();
    #pragma unroll
    for (int i=0;i<4;i++){
      int ch = i*256+tid;
      int lr = ch>>4, cq = (ch&15)*8;
      int r = r0 + pass*64 + lr;
      int c = c0 + cq;
      int which = c>>9, hh = (c>>6)&7, d = c&63;
      int bb = r>>12, n = r&4095;
      float scale = (which==0)? 0.125f : 1.f;
      sh8 ov;
      #pragma unroll
      for (int jj=0;jj<8;jj++) ov[jj] = (short)f2bf(tb[lr*132+cq+jj]*scale);
      u16* dst = which==0 ? q : (which==1 ? k : v);
      *(sh8*)(dst + (((size_t)(bb*8+hh))*4096 + n)*64 + d) = ov;
    }
  }
}

// ---------------- landmarks: mean over chunks of 16 ----------------
__global__ __launch_bounds__(64) void landmark_kernel(const u16* __restrict__ q,
    const u16* __restrict__ k, u16* __restrict__ ql, u16* __restrict__ kl){
  int bh = blockIdx.x, m = blockIdx.y, d = threadIdx.x;
  const u16* qp = q + (((size_t)bh*4096) + m*16)*64 + d;
  const u16* kp = k + (((size_t)bh*4096) + m*16)*64 + d;
  float sq=0, sk=0;
  #pragma unroll
  for (int j=0;j<16;j++){ sq += bf2f(qp[j*64]); sk += bf2f(kp[j*64]); }
  ql[((size_t)bh*256+m)*64+d] = f2bf(sq*(1.f/16.f));
  kl[((size_t)bh*256+m)*64+d] = f2bf(sk*(1.f/16.f));
}

// ---------------- attn2 = softmax(q_l @ k_l^T) -> bf16 hi/lo split (32x256x256) ----------------
__global__ __launch_bounds__(256) void attn2_kernel(const u16* __restrict__ ql,
    const u16* __restrict__ kl, u16* __restrict__ Xhi, u16* __restrict__ Xlo){
  int bh = blockIdx.x, rb = blockIdx.y;
  __shared__ short klds[256*72];
  const u16* kg = kl + (size_t)bh*256*64;
  int tid = threadIdx.x;
  #pragma unroll
  for (int i=0;i<8;i++){
    int c = i*256+tid, row = c>>3, kgi = c&7;
    *(sh8*)&klds[row*72+kgi*8] = *(const sh8*)(kg + row*64 + kgi*8);
  }
  __syncthreads();
  int r = rb*16 + (tid>>4), t = tid&15;
  const u16* qr = ql + ((size_t)bh*256 + r)*64;
  float qv[64];
  #pragma unroll
  for (int i=0;i<8;i++){
    sh8 v8 = *(const sh8*)(qr + i*8);
    #pragma unroll
    for (int j=0;j<8;j++) qv[i*8+j] = bf2f((u16)v8[j]);
  }
  float s[16];
  #pragma unroll
  for (int j=0;j<16;j++){
    int col = t + 16*j;
    const short* kr = &klds[col*72];
    float accv=0;
    #pragma unroll
    for (int i8=0;i8<8;i8++){
      sh8 kv = *(const sh8*)(kr + i8*8);
      #pragma unroll
      for (int jj=0;jj<8;jj++) accv += qv[i8*8+jj]*bf2f((u16)kv[jj]);
    }
    s[j]=accv;
  }
  float mx = s[0];
  #pragma unroll
  for (int j=1;j<16;j++) mx = fmaxf(mx, s[j]);
  #pragma unroll
  for (int o=1;o<16;o<<=1) mx = fmaxf(mx, __shfl_xor(mx,o));
  float sum=0;
  #pragma unroll
  for (int j=0;j<16;j++){ s[j] = __expf(s[j]-mx); sum += s[j]; }
  #pragma unroll
  for (int o=1;o<16;o<<=1) sum += __shfl_xor(sum,o);
  float inv = 1.f/sum;
  u16* Xh = Xhi + ((size_t)bh*256 + r)*256;
  u16* Xl = Xlo + ((size_t)bh*256 + r)*256;
  #pragma unroll
  for (int j=0;j<16;j++){
    float val = s[j]*inv;
    u16 hb = f2bf(val);
    Xh[t+16*j] = hb; Xl[t+16*j] = f2bf(val - bf2f(hb));
  }
}

// ---------------- max col-sum for pinv init (row-sum == 1 for softmax rows) ----------------
__global__ __launch_bounds__(256) void colrow_kernel(const u16* __restrict__ Xhi,
    const u16* __restrict__ Xlo, float* __restrict__ scal){
  int bh = blockIdx.x, t = threadIdx.x;
  const u16* xh = Xhi + (size_t)bh*65536;
  const u16* xl = Xlo + (size_t)bh*65536;
  float cs=0;
  for (int m=0;m<256;m++) cs += bf2f(xh[m*256+t]) + bf2f(xl[m*256+t]);
  #pragma unroll
  for (int o=32;o;o>>=1) cs = fmaxf(cs, __shfl_xor(cs,o));
  __shared__ float sb[4];
  if ((t&63)==0) sb[t>>6]=cs;
  __syncthreads();
  if (t==0){
    float mc = fmaxf(fmaxf(sb[0],sb[1]),fmaxf(sb[2],sb[3]));   // max col-sum -> "row"
    atomicMax((unsigned*)&scal[1], __float_as_uint(mc));
    atomicMax((unsigned*)&scal[0], __float_as_uint(1.0f));     // "col" = max row-sum of softmax == 1
  }
}

// ---------------- Z0 = X^T/(col*row) (hi/lo) and Z0T = X/(col*row), LDS-tiled ----------------
__global__ __launch_bounds__(256) void ztinit_kernel(const u16* __restrict__ Xhi,
    const u16* __restrict__ Xlo, const float* __restrict__ scal,
    u16* __restrict__ Zhi, u16* __restrict__ Zlo, u16* __restrict__ ZThi, u16* __restrict__ ZTlo){
  int bh = blockIdx.x; int xr0 = blockIdx.y*64, xc0 = blockIdx.z*64;
  __shared__ float tb[64*66];
  float inv = 1.f/(scal[0]*scal[1]);
  int tid = threadIdx.x;
  size_t mo = (size_t)bh*65536;
  int row = tid>>2, cof = (tid&3)*16;
  #pragma unroll
  for (int s2=0;s2<2;s2++){
    sh8 hv = *(const sh8*)(Xhi + mo + (size_t)(xr0+row)*256 + xc0+cof+s2*8);
    sh8 lv = *(const sh8*)(Xlo + mo + (size_t)(xr0+row)*256 + xc0+cof+s2*8);
    #pragma unroll
    for (int j=0;j<8;j++) tb[row*66 + cof+s2*8+j] = (bf2f((u16)hv[j])+bf2f((u16)lv[j]))*inv;
  }
  __syncthreads();
  int lc = tid&63;
  #pragma unroll
  for (int i=0;i<16;i++){
    int lr = i*4 + (tid>>6);
    float v1 = tb[lr*66+lc];
    u16 h1 = f2bf(v1);
    ZThi[mo + (size_t)(xr0+lr)*256 + xc0+lc] = h1;
    ZTlo[mo + (size_t)(xr0+lr)*256 + xc0+lc] = f2bf(v1 - bf2f(h1));
    float v2 = tb[lc*66+lr];
    u16 h2 = f2bf(v2);
    Zhi[mo + (size_t)(xc0+lr)*256 + xr0+lc] = h2;
    Zlo[mo + (size_t)(xc0+lr)*256 + xr0+lc] = f2bf(v2 - bf2f(h2));
  }
}

// ---------------- batched 256^3 matmul body, 64x32 tiles, 3-term, dbuf staging.
// LO: read lo planes; OUTLO: write lo planes.
// val = k0*(A@B) + k1*E1[rc] + k2*E2[rc]; writes C and/or CT. ----------------
template<int LO, int OUTLO>
__device__ __forceinline__ void pinv_body(
    const u16* __restrict__ Ahi, const u16* __restrict__ Alo,
    const u16* __restrict__ Bthi, const u16* __restrict__ Btlo,
    const u16* __restrict__ E1hi, const u16* __restrict__ E1lo,
    const u16* __restrict__ E2hi, const u16* __restrict__ E2lo,
    u16* __restrict__ Chi, u16* __restrict__ Clo,
    u16* __restrict__ CThi, u16* __restrict__ CTlo,
    float k0, float k1, float k2, int bh, int r0, int col0,
    short* smem){
  size_t mo = (size_t)bh*65536;
  int tid=threadIdx.x, lane=tid&63, w=tid>>6;
  int srow = tid>>2, skof = (tid&3)*8;
  bool doB = tid < 128;
  const u16* pA  = Ahi + mo + (size_t)(r0+srow)*256 + skof;
  const u16* pAl = (LO? Alo : Ahi) + mo + (size_t)(r0+srow)*256 + skof;
  const u16* pB  = Bthi + mo + (size_t)(col0+(srow&31))*256 + skof;
  const u16* pBl = (LO? Btlo : Bthi) + mo + (size_t)(col0+(srow&31))*256 + skof;
  float e1v[2][4], e2v[2][4];
  if (E1hi){
    #pragma unroll
    for (int fc=0;fc<2;fc++){
      #pragma unroll
      for (int j=0;j<4;j++){
        int lr = w*16+((lane>>4)<<2)+j, lc = fc*16+(lane&15);
        size_t o = mo+(size_t)(r0+lr)*256+col0+lc;
        e1v[fc][j] = bf2f(E1hi[o]) + (LO ? bf2f(E1lo[o]) : 0.f);
      }
    }
  }
  if (E2hi){
    #pragma unroll
    for (int fc=0;fc<2;fc++){
      #pragma unroll
      for (int j=0;j<4;j++){
        int lr = w*16+((lane>>4)<<2)+j, lc = fc*16+(lane&15);
        size_t o = mo+(size_t)(r0+lr)*256+col0+lc;
        e2v[fc][j] = bf2f(E2hi[o]) + (LO ? bf2f(E2lo[o]) : 0.f);
      }
    }
  }
  sh8 ra = *(const sh8*)pA;
  sh8 ral{}, rbv{}, rbl{};
  if (LO) ral = *(const sh8*)pAl;
  if (doB){ rbv = *(const sh8*)pB; if (LO) rbl = *(const sh8*)pBl; }
  f4 acc[2];
  acc[0]=0; acc[1]=0;
  for (int kt=0;kt<8;kt++){
    short* Ah = smem + (kt&1)*7680;
    short* Al = Ah + 2560; short* Bh = Ah + 5120; short* Bl = Ah + 6400;
    *(sh8*)&Ah[srow*40+skof] = ra;
    if (LO) *(sh8*)&Al[srow*40+skof] = ral;
    if (doB){
      *(sh8*)&Bh[(srow&31)*40+skof] = rbv;
      if (LO) *(sh8*)&Bl[(srow&31)*40+skof] = rbl;
    }
    __syncthreads();
    if (kt<7){
      int o2 = (kt+1)*32;
      ra = *(const sh8*)(pA+o2);
      if (LO) ral = *(const sh8*)(pAl+o2);
      if (doB){ rbv = *(const sh8*)(pB+o2); if (LO) rbl = *(const sh8*)(pBl+o2); }
    }
    int aoff = (w*16+(lane&15))*40 + ((lane>>4)<<3);
    sh8 ah = *(const sh8*)&Ah[aoff];
    sh8 al8{};
    if (LO) al8 = *(const sh8*)&Al[aoff];
    sh8 bh8[2], bl8[2];
    #pragma unroll
    for (int fc=0;fc<2;fc++){
      int boff = (fc*16+(lane&15))*40 + ((lane>>4)<<3);
      bh8[fc] = *(const sh8*)&Bh[boff];
      if (LO) bl8[fc] = *(const sh8*)&Bl[boff];
    }
    #pragma unroll
    for (int fc=0;fc<2;fc++){
      acc[fc] = __builtin_amdgcn_mfma_f32_16x16x32_bf16(ah, bh8[fc], acc[fc], 0,0,0);
      if (LO){
        acc[fc] = __builtin_amdgcn_mfma_f32_16x16x32_bf16(ah, bl8[fc], acc[fc], 0,0,0);
        acc[fc] = __builtin_amdgcn_mfma_f32_16x16x32_bf16(al8, bh8[fc], acc[fc], 0,0,0);
      }
    }
  }
  __syncthreads();
  float* tb = (float*)smem;   // 64x36 f32 = 9216B
  #pragma unroll
  for (int fc=0;fc<2;fc++){
    #pragma unroll
    for (int j=0;j<4;j++){
      int lr = w*16+((lane>>4)<<2)+j, lc = fc*16+(lane&15);
      float val = k0*acc[fc][j];
      if (E1hi) val += k1*e1v[fc][j];
      if (E2hi) val += k2*e2v[fc][j];
      tb[lr*36+lc] = val;
    }
  }
  __syncthreads();
  if (Chi){
    int lr2 = tid>>2, cq=(tid&3)*8;
    sh8 hi8, lo8;
    #pragma unroll
    for (int jj=0;jj<8;jj++){
      float v1 = tb[lr2*36+cq+jj];
      u16 hb = f2bf(v1);
      hi8[jj] = (short)hb; lo8[jj] = (short)f2bf(v1-bf2f(hb));
    }
    *(sh8*)(Chi + mo + (size_t)(r0+lr2)*256 + col0+cq) = hi8;
    if (OUTLO) *(sh8*)(Clo + mo + (size_t)(r0+lr2)*256 + col0+cq) = lo8;
  }
  if (CThi){
    int lrT = tid>>3, cqT=(tid&7)*8;
    sh8 hi8, lo8;
    #pragma unroll
    for (int jj=0;jj<8;jj++){
      float v2 = tb[(cqT+jj)*36 + lrT];
      u16 hb = f2bf(v2);
      hi8[jj] = (short)hb; lo8[jj] = (short)f2bf(v2-bf2f(hb));
    }
    *(sh8*)(CThi + mo + (size_t)(col0+lrT)*256 + r0+cqT) = hi8;
    if (OUTLO) *(sh8*)(CTlo + mo + (size_t)(col0+lrT)*256 + r0+cqT) = lo8;
  }
}

template<int LO, int OUTLO>
__global__ __launch_bounds__(256) void pinv_mm(
    const u16* Ahi, const u16* Alo, const u16* Bthi, const u16* Btlo,
    const u16* E1hi, const u16* E1lo, const u16* E2hi, const u16* E2lo,
    u16* Chi, u16* Clo, u16* CThi, u16* CTlo,
    float k0, float k1, float k2){
  __shared__ __align__(16) short smem[2*7680];
  pinv_body<LO,OUTLO>(Ahi,Alo,Bthi,Btlo,E1hi,E1lo,E2hi,E2lo,Chi,Clo,CThi,CTlo,
            k0,k1,k2, blockIdx.z, blockIdx.x*64, blockIdx.y*32, smem);
}

// combined Z' and T1' update: both = 3.25*E1 - 0.25*(E1@T3); which = z>>5
template<int LO, int OUTLO>
__global__ __launch_bounds__(256) void pinv_zupd(
    const u16* Zhi, const u16* Zlo, u16* ZnHi, u16* ZnLo,
    const u16* T1hi, const u16* T1lo,
    u16* TnChi, u16* TnClo, u16* TnThi, u16* TnTlo,
    const u16* Bthi, const u16* Btlo){
  __shared__ __align__(16) short smem[2*7680];
  int which = blockIdx.z >> 5, bh = blockIdx.z & 31;
  const u16* Ah = which ? T1hi : Zhi;
  const u16* Al = which ? T1lo : Zlo;
  u16* Ch  = which ? TnChi : ZnHi;
  u16* Cl  = which ? TnClo : ZnLo;
  u16* CTh = which ? TnThi : (u16*)0;
  u16* CTl = which ? TnTlo : (u16*)0;
  pinv_body<LO,OUTLO>(Ah,Al,Bthi,Btlo, Ah,Al, (u16*)0,(u16*)0, Ch,Cl,CTh,CTl,
            -0.25f, 3.25f, 0.f, bh, blockIdx.x*64, blockIdx.y*32, smem);
}

// ---------------- flash attn3: partials of softmax(ql@k^T)@v with online softmax ----------------
__global__ __launch_bounds__(256) void flash_out3(const u16* __restrict__ qlall,
    const u16* __restrict__ kall, const u16* __restrict__ vall,
    float* __restrict__ part, float2* __restrict__ pms){
  int mt = blockIdx.x, ks = blockIdx.y, bh = blockIdx.z;
  const u16* QL = qlall + ((size_t)bh*256 + mt*128)*64;
  const u16* K  = kall + ((size_t)bh*4096 + (size_t)ks*512)*64;
  const u16* V  = vall + ((size_t)bh*4096 + (size_t)ks*512)*64;
  float* O = part + ((size_t)(bh*8+ks)*256 + (size_t)mt*128)*64;
  float2* MS = pms + (size_t)(bh*8+ks)*256 + mt*128;
  __shared__ __align__(16) short kls[64*72];
  __shared__ __align__(16) short vts[64*72];
  __shared__ __align__(16) short Pls[128*72];
  int tid=threadIdx.x, lane=tid&63, w=tid>>6;
  sh8 aq[2][2];
  #pragma unroll
  for (int fr=0;fr<2;fr++){
    #pragma unroll
    for (int kc=0;kc<2;kc++)
      aq[fr][kc] = *(const sh8*)(QL + (size_t)(w*32+fr*16+(lane&15))*64 + kc*32 + ((lane>>4)<<3));
  }
  f4 oacc[2][4];
  #pragma unroll
  for (int fr=0;fr<2;fr++){
    #pragma unroll
    for (int fc=0;fc<4;fc++) oacc[fr][fc]=0;
  }
  float mrun[2][4], srun[2][4];
  #pragma unroll
  for (int fr=0;fr<2;fr++){
    #pragma unroll
    for (int j=0;j<4;j++){ mrun[fr][j]=-1e30f; srun[fr][j]=0.f; }
  }
  for (int kt=0;kt<8;kt++){
    __syncthreads();
    #pragma unroll
    for (int i=0;i<2;i++){
      int c=i*256+tid, row=c>>3, kg=c&7;
      *(sh8*)&kls[row*72+kg*8] = *(const sh8*)(K + (size_t)(kt*64+row)*64 + kg*8);
    }
    // V transpose-stage: vector sh8 global loads, scalar LDS writes (2-way bank)
    #pragma unroll
    for (int i=0;i<2;i++){
      int c=i*256+tid, row=c&63, kg=c>>6;   // kg in 0..3 (i=0), 4..7 (i=1)
      sh8 vv8 = *(const sh8*)(V + (size_t)(kt*64+row)*64 + kg*8);
      #pragma unroll
      for (int j=0;j<8;j++) vts[(kg*8+j)*72 + row] = vv8[j];
    }
    __syncthreads();
    f4 sacc[2][4];
    #pragma unroll
    for (int fr=0;fr<2;fr++){
      #pragma unroll
      for (int fc=0;fc<4;fc++) sacc[fr][fc]=0;
    }
    #pragma unroll
    for (int kc=0;kc<2;kc++){
      sh8 bk[4];
      #pragma unroll
      for (int fc=0;fc<4;fc++) bk[fc] = *(const sh8*)&kls[(fc*16+(lane&15))*72 + kc*32 + ((lane>>4)<<3)];
      #pragma unroll
      for (int fr=0;fr<2;fr++){
        #pragma unroll
        for (int fc=0;fc<4;fc++)
          sacc[fr][fc] = __builtin_amdgcn_mfma_f32_16x16x32_bf16(aq[fr][kc], bk[fc], sacc[fr][fc], 0,0,0);
      }
    }
    #pragma unroll
    for (int fr=0;fr<2;fr++){
      #pragma unroll
      for (int j=0;j<4;j++){
        float mt_ = fmaxf(fmaxf(sacc[fr][0][j],sacc[fr][1][j]), fmaxf(sacc[fr][2][j],sacc[fr][3][j]));
        #pragma unroll
        for (int o=1;o<16;o<<=1) mt_ = fmaxf(mt_, __shfl_xor(mt_,o));
        float mnew = fmaxf(mrun[fr][j], mt_);
        float scale = __expf(mrun[fr][j]-mnew);
        float e0 = __expf(sacc[fr][0][j]-mnew);
        float e1 = __expf(sacc[fr][1][j]-mnew);
        float e2 = __expf(sacc[fr][2][j]-mnew);
        float e3 = __expf(sacc[fr][3][j]-mnew);
        sacc[fr][0][j]=e0; sacc[fr][1][j]=e1; sacc[fr][2][j]=e2; sacc[fr][3][j]=e3;
        float sum = (e0+e1)+(e2+e3);
        #pragma unroll
        for (int o=1;o<16;o<<=1) sum += __shfl_xor(sum,o);
        srun[fr][j] = srun[fr][j]*scale + sum;
        mrun[fr][j] = mnew;
        #pragma unroll
        for (int fc=0;fc<4;fc++) oacc[fr][fc][j] *= scale;
      }
    }
    #pragma unroll
    for (int fr=0;fr<2;fr++){
      #pragma unroll
      for (int fc=0;fc<4;fc++){
        #pragma unroll
        for (int j=0;j<4;j++)
          Pls[(w*32+fr*16+((lane>>4)<<2)+j)*72 + fc*16+(lane&15)] = (short)f2bf(sacc[fr][fc][j]);
      }
    }
    #pragma unroll
    for (int kc=0;kc<2;kc++){
      sh8 pa[2], bv[4];
      #pragma unroll
      for (int fr=0;fr<2;fr++) pa[fr] = *(const sh8*)&Pls[(w*32+fr*16+(lane&15))*72 + kc*32 + ((lane>>4)<<3)];
      #pragma unroll
      for (int fc=0;fc<4;fc++) bv[fc] = *(const sh8*)&vts[(fc*16+(lane&15))*72 + kc*32 + ((lane>>4)<<3)];
      #pragma unroll
      for (int fr=0;fr<2;fr++){
        #pragma unroll
        for (int fc=0;fc<4;fc++)
          oacc[fr][fc] = __builtin_amdgcn_mfma_f32_16x16x32_bf16(pa[fr], bv[fc], oacc[fr][fc], 0,0,0);
      }
    }
  }
  #pragma unroll
  for (int fr=0;fr<2;fr++){
    #pragma unroll
    for (int fc=0;fc<4;fc++){
      #pragma unroll
      for (int j=0;j<4;j++)
        O[(size_t)(w*32+fr*16+((lane>>4)<<2)+j)*64 + fc*16+(lane&15)] = oacc[fr][fc][j];
    }
  }
  if ((lane&15)==0){
    #pragma unroll
    for (int fr=0;fr<2;fr++){
      #pragma unroll
      for (int j=0;j<4;j++)
        MS[w*32+fr*16+((lane>>4)<<2)+j] = make_float2(mrun[fr][j], srun[fr][j]);
    }
  }
}

// ---------------- flash merge of 8 K-split partials ----------------
__global__ __launch_bounds__(256) void reduce_o3(const float* __restrict__ part,
    const float2* __restrict__ pms, float* __restrict__ o3){
  int idx = blockIdx.x*256+threadIdx.x;
  int d = idx&63, row = (idx>>6)&255, bh = idx>>14;
  float2 ms[8];
  float M = -1e30f;
  #pragma unroll
  for (int ks=0;ks<8;ks++){
    ms[ks] = pms[(size_t)(bh*8+ks)*256 + row];
    M = fmaxf(M, ms[ks].x);
  }
  float S=0.f, acc=0.f;
  #pragma unroll
  for (int ks=0;ks<8;ks++){
    float e = __expf(ms[ks].x - M);
    S += e*ms[ks].y;
    acc += e*part[((size_t)(bh*8+ks)*256 + row)*64 + d];
  }
  o3[idx] = acc/S;
}

// ---------------- Wt[d][m] = (z @ out3)[m][d] bf16, z in hi/lo ----------------
__global__ __launch_bounds__(256) void wt_kernel(const u16* __restrict__ Zhi,
    const u16* __restrict__ Zlo, const float* __restrict__ o3, u16* __restrict__ Wt){
  int bh = blockIdx.x; int m = blockIdx.y*4 + (threadIdx.x>>6); int d = threadIdx.x&63;
  const u16* zh = Zhi + ((size_t)bh*256 + m)*256;
  const u16* zl = Zlo + ((size_t)bh*256 + m)*256;
  const float* op = o3 + (size_t)bh*256*64 + d;
  float accv = 0;
  for (int kk=0;kk<256;kk++) accv += (bf2f(zh[kk])+bf2f(zl[kk]))*op[kk*64];
  Wt[((size_t)bh*64 + d)*256 + m] = f2bf(accv);
}

// ---------------- fused out1 = softmax_row(q @ kl^T) @ W, 64 q-rows/block, bf16 out ----------------
__global__ __launch_bounds__(256) void fused_out1(const u16* __restrict__ q,
    const u16* __restrict__ klall, const u16* __restrict__ Wtall, u16* __restrict__ Oall){
  int rb = blockIdx.x, bh = blockIdx.y;
  __shared__ __align__(16) short sm[18432];   // Bs 256x72 ; then P (64x268); then out bounce
  short* Bs = sm; short* P = sm;
  int tid=threadIdx.x, lane=tid&63, w=tid>>6;
  const u16* qb  = q + ((size_t)bh*4096 + (size_t)rb*64)*64;
  const u16* klb = klall + (size_t)bh*256*64;
  const u16* Wt  = Wtall + (size_t)bh*64*256;
  #pragma unroll
  for (int i=0;i<8;i++){
    int c = i*256+tid, row = c>>3, kg = c&7;
    *(sh8*)&Bs[row*72+kg*8] = *(const sh8*)(klb + row*64 + kg*8);
  }
  const u16* qrow = qb + (size_t)(w*16+(lane&15))*64 + ((lane>>4)<<3);
  sh8 a0 = *(const sh8*)(qrow);
  sh8 a1 = *(const sh8*)(qrow + 32);
  __syncthreads();
  // S = q @ kl^T : 16 rows/wave x 256 cols
  f4 acc[16];
  #pragma unroll
  for (int fc=0;fc<16;fc++){
    sh8 b0 = *(const sh8*)&Bs[(fc*16+(lane&15))*72 + ((lane>>4)<<3)];
    sh8 b1 = *(const sh8*)&Bs[(fc*16+(lane&15))*72 + 32 + ((lane>>4)<<3)];
    acc[fc]=0;
    acc[fc] = __builtin_amdgcn_mfma_f32_16x16x32_bf16(a0, b0, acc[fc], 0,0,0);
    acc[fc] = __builtin_amdgcn_mfma_f32_16x16x32_bf16(a1, b1, acc[fc], 0,0,0);
  }
  // issue first Wt prefetch EARLY: latency hides under softmax + P-write (T14 pattern)
  sh8 bqA[4], bqB[4];
  #pragma unroll
  for (int fc2=0;fc2<4;fc2++){
    int d = fc2*16 + (lane&15);
    bqA[fc2] = *(const sh8*)(Wt + (size_t)d*256 + ((lane>>4))*8);
  }
  // in-register row softmax, tree-reduced
  float inv_[4];
  #pragma unroll
  for (int j=0;j<4;j++){
    float m0 = fmaxf(fmaxf(acc[0][j],acc[1][j]), fmaxf(acc[2][j],acc[3][j]));
    float m1 = fmaxf(fmaxf(acc[4][j],acc[5][j]), fmaxf(acc[6][j],acc[7][j]));
    float m2 = fmaxf(fmaxf(acc[8][j],acc[9][j]), fmaxf(acc[10][j],acc[11][j]));
    float m3 = fmaxf(fmaxf(acc[12][j],acc[13][j]), fmaxf(acc[14][j],acc[15][j]));
    float mx = fmaxf(fmaxf(m0,m1), fmaxf(m2,m3));
    #pragma unroll
    for (int o=1;o<16;o<<=1) mx = fmaxf(mx, __shfl_xor(mx,o));
    float e[16];
    #pragma unroll
    for (int fc=0;fc<16;fc++){ e[fc]=__expf(acc[fc][j]-mx); acc[fc][j]=e[fc]; }
    float s = (((e[0]+e[1])+(e[2]+e[3])) + ((e[4]+e[5])+(e[6]+e[7])))
            + (((e[8]+e[9])+(e[10]+e[11])) + ((e[12]+e[13])+(e[14]+e[15])));
    #pragma unroll
    for (int o=1;o<16;o<<=1) s += __shfl_xor(s,o);
    inv_[j] = 1.f/s;
  }
  __syncthreads();
  #pragma unroll
  for (int fc=0;fc<16;fc++){
    #pragma unroll
    for (int j=0;j<4;j++){
      int row = w*16 + ((lane>>4)<<2) + j, col = fc*16 + (lane&15);
      P[row*268 + col] = (short)f2bf(acc[fc][j]*inv_[j]);
    }
  }
  __syncthreads();
  // out = P @ W, K=256; Wt b-fragments software-pipelined 2-deep from global
  f4 acc2[4];
  #pragma unroll
  for (int fc2=0;fc2<4;fc2++) acc2[fc2]=0;
  #pragma unroll
  for (int kp=0;kp<4;kp++){
    int kc0 = kp*2, kc1 = kp*2+1;
    #pragma unroll
    for (int fc2=0;fc2<4;fc2++){
      int d = fc2*16 + (lane&15);
      bqB[fc2] = *(const sh8*)(Wt + (size_t)d*256 + (kc1*4+(lane>>4))*8);
    }
    sh8 a = *(const sh8*)&P[(w*16+(lane&15))*268 + kc0*32 + ((lane>>4)<<3)];
    #pragma unroll
    for (int fc2=0;fc2<4;fc2++)
      acc2[fc2] = __builtin_amdgcn_mfma_f32_16x16x32_bf16(a, bqA[fc2], acc2[fc2], 0,0,0);
    if (kp<3){
      #pragma unroll
      for (int fc2=0;fc2<4;fc2++){
        int d = fc2*16 + (lane&15);
        bqA[fc2] = *(const sh8*)(Wt + (size_t)d*256 + ((kc1+1)*4+(lane>>4))*8);
      }
    }
    sh8 a2 = *(const sh8*)&P[(w*16+(lane&15))*268 + kc1*32 + ((lane>>4)<<3)];
    #pragma unroll
    for (int fc2=0;fc2<4;fc2++)
      acc2[fc2] = __builtin_amdgcn_mfma_f32_16x16x32_bf16(a2, bqB[fc2], acc2[fc2], 0,0,0);
  }
  // bounce to LDS, emit coalesced 16B bf16 stores
  __syncthreads();
  u16* otb = (u16*)sm;
  #pragma unroll
  for (int fc2=0;fc2<4;fc2++){
    #pragma unroll
    for (int j=0;j<4;j++)
      otb[(w*16+((lane>>4)<<2)+j)*72 + fc2*16+(lane&15)] = f2bf(acc2[fc2][j]);
  }
  __syncthreads();
  u16* O = Oall + ((size_t)bh*4096 + (size_t)rb*64)*64;
  #pragma unroll
  for (int i=0;i<2;i++){
    int ch = i*256+tid; int lr = ch>>3, cq = (ch&7)*8;
    sh8 ov = *(sh8*)&otb[lr*72+cq];
    *(sh8*)(O + (size_t)lr*64 + cq) = ov;
  }
}

// ---------------- combine: register-window depthwise conv + residual add (bf16 in) ----------------
__global__ __launch_bounds__(256) void combine_kernel(const u16* __restrict__ out1,
    const u16* __restrict__ v, const float* __restrict__ wres, u16* __restrict__ oc){
  int bh = blockIdx.x; int hh = bh&7, bb = bh>>3;
  int n0 = blockIdx.y*64;
  int tid = threadIdx.x, d = tid&63, sub = tid>>6;
  int nbase = n0 + sub*16;
  const u16* vb = v + ((size_t)bh*4096)*64 + d;
  float w_[33];
  #pragma unroll
  for (int j=0;j<33;j++) w_[j] = wres[hh*33+j];
  float vv[48];
  #pragma unroll
  for (int i=0;i<48;i++){
    int nn = nbase + i - 16;
    vv[i] = (nn>=0 && nn<4096) ? bf2f(vb[(size_t)nn*64]) : 0.f;
  }
  #pragma unroll
  for (int r=0;r<16;r++){
    int n = nbase + r;
    float acc = bf2f(out1[(((size_t)bh*4096)+n)*64 + d]);
    #pragma unroll
    for (int j=0;j<33;j++) acc += w_[j]*vv[r+j];
    oc[((size_t)(bb*4096+n))*512 + hh*64 + d] = f2bf(acc);
  }
}

// ---------------- final: out = x + ocomb @ w_out + b_out ----------------
__global__ __launch_bounds__(256) void gemm_final(const u16* __restrict__ A,
    const u16* __restrict__ Bt, const float* __restrict__ x, const float* __restrict__ bo,
    float* __restrict__ out){
  __shared__ short As[128*72], Bs[128*72];
  int r0 = blockIdx.x*128, c0 = blockIdx.y*128;
  int tid = threadIdx.x, lane = tid&63, w = tid>>6;
  int wr = w>>1, wc = w&1;
  f4 acc[4][4];
  #pragma unroll
  for (int i=0;i<4;i++){
    #pragma unroll
    for (int j=0;j<4;j++) acc[i][j]=0;
  }
  for (int kt=0;kt<8;kt++){
    __syncthreads();
    #pragma unroll
    for (int i=0;i<4;i++){
      int c = i*256+tid, row = c>>3, kg = c&7;
      *(sh8*)&As[row*72+kg*8] = *(const sh8*)(A  + (size_t)(r0+row)*512 + kt*64 + kg*8);
      *(sh8*)&Bs[row*72+kg*8] = *(const sh8*)(Bt + (size_t)(c0+row)*512 + kt*64 + kg*8);
    }
    __syncthreads();
    #pragma unroll
    for (int kc=0;kc<2;kc++){
      sh8 a[4], bq[4];
      #pragma unroll
      for (int fr=0;fr<4;fr++) a[fr]  = *(const sh8*)&As[(wr*64+fr*16+(lane&15))*72 + kc*32 + ((lane>>4)<<3)];
      #pragma unroll
      for (int fc=0;fc<4;fc++) bq[fc] = *(const sh8*)&Bs[(wc*64+fc*16+(lane&15))*72 + kc*32 + ((lane>>4)<<3)];
      #pragma unroll
      for (int fr=0;fr<4;fr++){
        #pragma unroll
        for (int fc=0;fc<4;fc++)
          acc[fr][fc] = __builtin_amdgcn_mfma_f32_16x16x32_bf16(a[fr], bq[fc], acc[fr][fc], 0,0,0);
      }
    }
  }
  #pragma unroll
  for (int fr=0;fr<4;fr++){
    #pragma unroll
    for (int fc=0;fc<4;fc++){
      #pragma unroll
      for (int j=0;j<4;j++){
        int r = r0 + wr*64 + fr*16 + ((lane>>4)<<2) + j;
        int c = c0 + wc*64 + fc*16 + (lane&15);
        out[(size_t)r*512+c] = x[(size_t)r*512+c] + acc[fr][fc][j] + bo[c];
      }
    }
  }
}

extern "C" void kernel_launch(void* const* d_in, const int* in_sizes, int n_in,
                              void* d_out, int out_size, void* d_ws, size_t ws_size,
                              hipStream_t stream){
  const float* x    = (const float*)d_in[0];
  const float* lnw  = (const float*)d_in[1];
  const float* lnb  = (const float*)d_in[2];
  const float* wqkv = (const float*)d_in[3];
  const float* wout = (const float*)d_in[4];
  const float* bout = (const float*)d_in[5];
  const float* wres = (const float*)d_in[6];
  float* out = (float*)d_out;

  char* ws = (char*)d_ws;
  size_t off = 0;
  auto alloc = [&](size_t bytes)->void*{ void* p = ws + off; off += (bytes + 255) & ~(size_t)255; return p; };
  u16* h      = (u16*)alloc((size_t)NT_*512*2);          // aliased later as oc
  u16* wqkvT  = (u16*)alloc((size_t)1536*512*2);
  u16* woutT  = (u16*)alloc((size_t)512*512*2);
  u16* k      = (u16*)alloc((size_t)BH_*4096*64*2);
  u16* v      = (u16*)alloc((size_t)BH_*4096*64*2);
  u16* q      = (u16*)alloc((size_t)BH_*4096*64*2);
  float* part = (float*)alloc((size_t)BH_*8*256*64*4);   // ZT tmp aliases here during pinv
  float2* pms = (float2*)alloc((size_t)BH_*8*256*8);
  u16* ql     = (u16*)alloc((size_t)BH_*256*64*2);
  u16* kl     = (u16*)alloc((size_t)BH_*256*64*2);
  u16* ZaChi  = (u16*)alloc((size_t)BH_*65536*2);        // final z lands here
  u16* ZaClo  = (u16*)alloc((size_t)BH_*65536*2);
  u16* ZbChi  = (u16*)alloc((size_t)BH_*65536*2);
  u16* ZbClo  = (u16*)alloc((size_t)BH_*65536*2);
  u16* scratch = (u16*)alloc((size_t)BH_*65536*2*16);    // 64 MiB pinv scratch; out1 aliases
  float* o3   = (float*)alloc((size_t)BH_*256*64*4);
  u16* Wt     = (u16*)alloc((size_t)BH_*64*256*2);
  float* scal = (float*)alloc(256);
  u16* out1   = scratch;        // scratch dead after pinv+wt
  u16* oc     = h;              // h dead after qkv gemm

  const size_t C1 = (size_t)BH_*65536;
  u16* base = scratch;
  u16* Xhi   = base + 0*C1;  u16* Xlo   = base + 1*C1;
  u16* T1aCh = base + 2*C1;  u16* T1aCl = base + 3*C1;
  u16* T1aTh = base + 4*C1;  u16* T1aTl = base + 5*C1;
  u16* T1bCh = base + 6*C1;  u16* T1bCl = base + 7*C1;
  u16* T1bTh = base + 8*C1;  u16* T1bTl = base + 9*C1;
  u16* SCh   = base +10*C1;  u16* SCl   = base +11*C1;   // Z0T aliases here (dead after T1_0)
  u16* STh   = base +12*C1;  u16* STl   = base +13*C1;
  u16* T3h   = base +14*C1;  u16* T3l   = base +15*C1;
  u16* Z0Th  = SCh;          u16* Z0Tl  = SCl;
  u16* ZTth  = (u16*)part;   u16* ZTtl  = ZTth + C1;     // Z^T tmp for refresh (part dead in pinv)

  prep_kernel<<<NT_ + (512*1536+512*512+255)/256, 256, 0, stream>>>(
      x, lnw, lnb, h, wqkv, wqkvT, wout, woutT);
  gemm_qkv<<<dim3(128,12,1), 256, 0, stream>>>(h, wqkvT, q, k, v);
  landmark_kernel<<<dim3(32,256,1), 64, 0, stream>>>(q, k, ql, kl);
  attn2_kernel<<<dim3(32,16,1), 256, 0, stream>>>(ql, kl, Xhi, Xlo);
  hipMemsetAsync(scal, 0, 8, stream);
  colrow_kernel<<<32, 256, 0, stream>>>(Xhi, Xlo, scal);
  ztinit_kernel<<<dim3(32,4,4), 256, 0, stream>>>(Xhi, Xlo, scal, ZaChi, ZaClo, Z0Th, Z0Tl);

  u16* nul = (u16*)0;
  // T1_0 = X @ Z0  (hi-only outputs: lo planes unread before the it==4 refresh)
  pinv_mm<1,0><<<dim3(4,8,32),256,0,stream>>>(Xhi,Xlo, Z0Th,Z0Tl, nul,nul,nul,nul,
      T1aCh,T1aCl, T1aTh,T1aTl, 1.f,0.f,0.f);
  u16 *TcCh=T1aCh,*TcCl=T1aCl,*TcTh=T1aTh,*TcTl=T1aTl;
  u16 *TnCh=T1bCh,*TnCl=T1bCl,*TnTh=T1bTh,*TnTl=T1bTl;
  u16 *Zch=ZaChi,*Zcl=ZaClo, *Znh=ZbChi,*Znl=ZbClo;
  for (int it=0; it<6; it++){
    if (it==4){
      // refresh true residual: T1 = X @ Z  (Z^T captured at it==3)
      pinv_mm<1,1><<<dim3(4,8,32),256,0,stream>>>(Xhi,Xlo, ZTth,ZTtl, nul,nul,nul,nul,
          TnCh,TnCl, TnTh,TnTl, 1.f,0.f,0.f);
      u16* t;
      t=TcCh;TcCh=TnCh;TnCh=t; t=TcCl;TcCl=TnCl;TnCl=t;
      t=TcTh;TcTh=TnTh;TnTh=t; t=TcTl;TcTl=TnTl;TnTl=t;
    }
    if (it<4){
      pinv_mm<0,0><<<dim3(4,8,32),256,0,stream>>>(TcCh,TcCl, TcTh,TcTl, nul,nul,nul,nul,
          SCh,SCl, STh,STl, 1.f,0.f,0.f);
      pinv_mm<0,0><<<dim3(4,8,32),256,0,stream>>>(TcCh,TcCl, STh,STl, TcCh,TcCl, SCh,SCl,
          nul,nul, T3h,T3l, 1.f,15.f,-7.f);
    } else {
      pinv_mm<1,1><<<dim3(4,8,32),256,0,stream>>>(TcCh,TcCl, TcTh,TcTl, nul,nul,nul,nul,
          SCh,SCl, STh,STl, 1.f,0.f,0.f);
      pinv_mm<1,1><<<dim3(4,8,32),256,0,stream>>>(TcCh,TcCl, STh,STl, TcCh,TcCl, SCh,SCl,
          nul,nul, T3h,T3l, 1.f,15.f,-7.f);
    }
    if (it<3){
      pinv_zupd<0,0><<<dim3(4,8,64),256,0,stream>>>(Zch,Zcl, Znh,Znl,
          TcCh,TcCl, TnCh,TnCl, TnTh,TnTl, T3h,T3l);
      u16* t;
      t=Zch;Zch=Znh;Znh=t; t=Zcl;Zcl=Znl;Znl=t;
      t=TcCh;TcCh=TnCh;TnCh=t; t=TcCl;TcCl=TnCl;TnCl=t;
      t=TcTh;TcTh=TnTh;TnTh=t; t=TcTl;TcTl=TnTl;TnTl=t;
    } else if (it==3){
      // Z' only (T1' of it3 is replaced by the it4 refresh); capture Z'^T for refresh
      pinv_mm<0,1><<<dim3(4,8,32),256,0,stream>>>(Zch,Zcl, T3h,T3l, Zch,Zcl, nul,nul,
          Znh,Znl, ZTth,ZTtl, -0.25f,3.25f,0.f);
      u16* t;
      t=Zch;Zch=Znh;Znh=t; t=Zcl;Zcl=Znl;Znl=t;
    } else if (it==4){
      pinv_zupd<1,1><<<dim3(4,8,64),256,0,stream>>>(Zch,Zcl, Znh,Znl,
          TcCh,TcCl, TnCh,TnCl, TnTh,TnTl, T3h,T3l);
      u16* t;
      t=Zch;Zch=Znh;Znh=t; t=Zcl;Zcl=Znl;Znl=t;
      t=TcCh;TcCh=TnCh;TnCh=t; t=TcCl;TcCl=TnCl;TnCl=t;
      t=TcTh;TcTh=TnTh;TnTh=t; t=TcTl;TcTl=TnTl;TnTl=t;
    } else {
      pinv_mm<1,1><<<dim3(4,8,32),256,0,stream>>>(Zch,Zcl, T3h,T3l, Zch,Zcl, nul,nul,
          Znh,Znl, nul,nul, -0.25f,3.25f,0.f);
    }
  }
  // Z swaps at it0..4 (5 swaps): final write lands in ZaChi/ZaClo

  flash_out3<<<dim3(2,8,32),256,0,stream>>>(ql, k, v, part, pms);
  reduce_o3<<<2048, 256, 0, stream>>>(part, pms, o3);
  wt_kernel<<<dim3(32,64,1),256,0,stream>>>(ZaChi, ZaClo, o3, Wt);
  fused_out1<<<dim3(64,32,1),256,0,stream>>>(q, kl, Wt, out1);
  combine_kernel<<<dim3(32,64,1),256,0,stream>>>(out1, v, wres, oc);
  gemm_final<<<dim3(128,4,1),256,0,stream>>>(oc, woutT, x, bout, out);
}

// Round 18
// 508.245 us; speedup vs baseline: 1.0109x; 1.0109x over previous
//
#include <hip/hip_runtime.h>
#include <hip/hip_bf16.h>
#include <hip/hip_fp16.h>

// Nystromformer layer: b=4, n=4096, dim=512, heads=8, dim_head=64, m=256, pinv_iters=6
#define B_ 4
#define H_ 8
#define N_ 4096
#define DH_ 64
#define D_ 512
#define M_ 256
#define BH_ 32
#define NT_ 16384

typedef unsigned short u16;
using sh8 = __attribute__((ext_vector_type(8))) short;
using f4  = __attribute__((ext_vector_type(4))) float;

__device__ __forceinline__ float bf2f(u16 u){ return __uint_as_float(((unsigned)u)<<16); }
__device__ __forceinline__ u16 f2bf(float f){
  unsigned u = __float_as_uint(f);
  u += 0x7fffu + ((u>>16)&1u);
  return (u16)(u>>16);
}

// ---------------- prep: LayerNorm (blocks 0..NT_-1) + weight transpose-casts ----------------
__global__ __launch_bounds__(256) void prep_kernel(const float* __restrict__ x,
    const float* __restrict__ w, const float* __restrict__ b, u16* __restrict__ h,
    const float* __restrict__ wqkv, u16* __restrict__ wqkvT,
    const float* __restrict__ wout, u16* __restrict__ woutT){
  int t = threadIdx.x;
  if (blockIdx.x < NT_){
    int row = blockIdx.x;
    const float2* xr = (const float2*)(x + (size_t)row*D_);
    float2 v = xr[t];
    float s = v.x+v.y, ss = v.x*v.x+v.y*v.y;
    #pragma unroll
    for (int o=32;o;o>>=1){ s += __shfl_xor(s,o); ss += __shfl_xor(ss,o); }
    __shared__ float sb[4], sb2[4];
    if ((t&63)==0){ sb[t>>6]=s; sb2[t>>6]=ss; }
    __syncthreads();
    float ts  = sb[0]+sb[1]+sb[2]+sb[3];
    float tss = sb2[0]+sb2[1]+sb2[2]+sb2[3];
    float mean = ts*(1.f/D_);
    float var  = tss*(1.f/D_) - mean*mean;
    float rstd = rsqrtf(var+1e-5f);
    int c = 2*t;
    float o0 = (v.x-mean)*rstd*w[c]   + b[c];
    float o1 = (v.y-mean)*rstd*w[c+1] + b[c+1];
    u16* hr = h + (size_t)row*D_;
    hr[c] = f2bf(o0); hr[c+1] = f2bf(o1);
  } else {
    int idx = (blockIdx.x - NT_)*256 + t;
    if (idx < 512*1536){
      int k = idx/1536, n = idx - k*1536;
      wqkvT[(size_t)n*512 + k] = f2bf(wqkv[idx]);
    } else {
      int i2 = idx - 512*1536;
      if (i2 < 512*512){
        int k = i2>>9, n = i2&511;
        woutT[(size_t)n*512 + k] = f2bf(wout[i2]);
      }
    }
  }
}

// ---------------- QKV GEMM: h(16384x512) @ wqkvT(1536x512)^T, LDS-bounced epilogue ----------------
__global__ __launch_bounds__(256) void gemm_qkv(const u16* __restrict__ A,
    const u16* __restrict__ Bt, u16* __restrict__ q, u16* __restrict__ k, u16* __restrict__ v){
  __shared__ __align__(16) short sm[2*128*72];
  short* As = sm; short* Bs = sm + 128*72;
  int r0 = blockIdx.x*128, c0 = blockIdx.y*128;
  int tid = threadIdx.x, lane = tid&63, w = tid>>6;
  int wr = w>>1, wc = w&1;
  f4 acc[4][4];
  #pragma unroll
  for (int i=0;i<4;i++){
    #pragma unroll
    for (int j=0;j<4;j++) acc[i][j]=0;
  }
  for (int kt=0;kt<8;kt++){
    __syncthreads();
    #pragma unroll
    for (int i=0;i<4;i++){
      int c = i*256+tid, row = c>>3, kg = c&7;
      *(sh8*)&As[row*72+kg*8] = *(const sh8*)(A + (size_t)(r0+row)*512 + kt*64 + kg*8);
      *(sh8*)&Bs[row*72+kg*8] = *(const sh8*)(Bt + (size_t)(c0+row)*512 + kt*64 + kg*8);
    }
    __syncthreads();
    #pragma unroll
    for (int kc=0;kc<2;kc++){
      sh8 a[4], bq[4];
      #pragma unroll
      for (int fr=0;fr<4;fr++) a[fr]  = *(const sh8*)&As[(wr*64+fr*16+(lane&15))*72 + kc*32 + ((lane>>4)<<3)];
      #pragma unroll
      for (int fc=0;fc<4;fc++) bq[fc] = *(const sh8*)&Bs[(wc*64+fc*16+(lane&15))*72 + kc*32 + ((lane>>4)<<3)];
      #pragma unroll
      for (int fr=0;fr<4;fr++){
        #pragma unroll
        for (int fc=0;fc<4;fc++)
          acc[fr][fc] = __builtin_amdgcn_mfma_f32_16x16x32_bf16(a[fr], bq[fc], acc[fr][fc], 0,0,0);
      }
    }
  }
  // epilogue: bounce 64x128 f32 half-tiles through LDS, emit 16B bf16 stores
  float* tb = (float*)sm;   // 64x132 f32 = 33792B
  #pragma unroll 1
  for (int pass=0; pass<2; pass++){
    __syncthreads();
    if (wr==pass){
      #pragma unroll
      for (int fr=0;fr<4;fr++){
        #pragma unroll
        for (int fc=0;fc<4;fc++){
          #pragma unroll
          for (int j=0;j<4;j++)
            tb[(fr*16+((lane>>4)<<2)+j)*132 + wc*64+fc*16+(lane&15)] = acc[fr][fc][j];
        }
      }
    }
    __syncthreads();
    #pragma unroll
    for (int i=0;i<4;i++){
      int ch = i*256+tid;
      int lr = ch>>4, cq = (ch&15)*8;
      int r = r0 + pass*64 + lr;
      int c = c0 + cq;
      int which = c>>9, hh = (c>>6)&7, d = c&63;
      int bb = r>>12, n = r&4095;
      float scale = (which==0)? 0.125f : 1.f;
      sh8 ov;
      #pragma unroll
      for (int jj=0;jj<8;jj++) ov[jj] = (short)f2bf(tb[lr*132+cq+jj]*scale);
      u16* dst = which==0 ? q : (which==1 ? k : v);
      *(sh8*)(dst + (((size_t)(bb*8+hh))*4096 + n)*64 + d) = ov;
    }
  }
}

// ---------------- landmarks: mean over chunks of 16 ----------------
__global__ __launch_bounds__(64) void landmark_kernel(const u16* __restrict__ q,
    const u16* __restrict__ k, u16* __restrict__ ql, u16* __restrict__ kl){
  int bh = blockIdx.x, m = blockIdx.y, d = threadIdx.x;
  const u16* qp = q + (((size_t)bh*4096) + m*16)*64 + d;
  const u16* kp = k + (((size_t)bh*4096) + m*16)*64 + d;
  float sq=0, sk=0;
  #pragma unroll
  for (int j=0;j<16;j++){ sq += bf2f(qp[j*64]); sk += bf2f(kp[j*64]); }
  ql[((size_t)bh*256+m)*64+d] = f2bf(sq*(1.f/16.f));
  kl[((size_t)bh*256+m)*64+d] = f2bf(sk*(1.f/16.f));
}

// ---------------- attn2 = softmax(q_l @ k_l^T) -> bf16 hi/lo split (32x256x256) ----------------
__global__ __launch_bounds__(256) void attn2_kernel(const u16* __restrict__ ql,
    const u16* __restrict__ kl, u16* __restrict__ Xhi, u16* __restrict__ Xlo){
  int bh = blockIdx.x, rb = blockIdx.y;
  __shared__ short klds[256*72];
  const u16* kg = kl + (size_t)bh*256*64;
  int tid = threadIdx.x;
  #pragma unroll
  for (int i=0;i<8;i++){
    int c = i*256+tid, row = c>>3, kgi = c&7;
    *(sh8*)&klds[row*72+kgi*8] = *(const sh8*)(kg + row*64 + kgi*8);
  }
  __syncthreads();
  int r = rb*16 + (tid>>4), t = tid&15;
  const u16* qr = ql + ((size_t)bh*256 + r)*64;
  float qv[64];
  #pragma unroll
  for (int i=0;i<8;i++){
    sh8 v8 = *(const sh8*)(qr + i*8);
    #pragma unroll
    for (int j=0;j<8;j++) qv[i*8+j] = bf2f((u16)v8[j]);
  }
  float s[16];
  #pragma unroll
  for (int j=0;j<16;j++){
    int col = t + 16*j;
    const short* kr = &klds[col*72];
    float accv=0;
    #pragma unroll
    for (int i8=0;i8<8;i8++){
      sh8 kv = *(const sh8*)(kr + i8*8);
      #pragma unroll
      for (int jj=0;jj<8;jj++) accv += qv[i8*8+jj]*bf2f((u16)kv[jj]);
    }
    s[j]=accv;
  }
  float mx = s[0];
  #pragma unroll
  for (int j=1;j<16;j++) mx = fmaxf(mx, s[j]);
  #pragma unroll
  for (int o=1;o<16;o<<=1) mx = fmaxf(mx, __shfl_xor(mx,o));
  float sum=0;
  #pragma unroll
  for (int j=0;j<16;j++){ s[j] = __expf(s[j]-mx); sum += s[j]; }
  #pragma unroll
  for (int o=1;o<16;o<<=1) sum += __shfl_xor(sum,o);
  float inv = 1.f/sum;
  u16* Xh = Xhi + ((size_t)bh*256 + r)*256;
  u16* Xl = Xlo + ((size_t)bh*256 + r)*256;
  #pragma unroll
  for (int j=0;j<16;j++){
    float val = s[j]*inv;
    u16 hb = f2bf(val);
    Xh[t+16*j] = hb; Xl[t+16*j] = f2bf(val - bf2f(hb));
  }
}

// ---------------- max col-sum for pinv init (row-sum == 1 for softmax rows) ----------------
__global__ __launch_bounds__(256) void colrow_kernel(const u16* __restrict__ Xhi,
    const u16* __restrict__ Xlo, float* __restrict__ scal){
  int bh = blockIdx.x, t = threadIdx.x;
  const u16* xh = Xhi + (size_t)bh*65536;
  const u16* xl = Xlo + (size_t)bh*65536;
  float cs=0;
  for (int m=0;m<256;m++) cs += bf2f(xh[m*256+t]) + bf2f(xl[m*256+t]);
  #pragma unroll
  for (int o=32;o;o>>=1) cs = fmaxf(cs, __shfl_xor(cs,o));
  __shared__ float sb[4];
  if ((t&63)==0) sb[t>>6]=cs;
  __syncthreads();
  if (t==0){
    float mc = fmaxf(fmaxf(sb[0],sb[1]),fmaxf(sb[2],sb[3]));   // max col-sum -> "row"
    atomicMax((unsigned*)&scal[1], __float_as_uint(mc));
    atomicMax((unsigned*)&scal[0], __float_as_uint(1.0f));     // "col" = max row-sum of softmax == 1
  }
}

// ---------------- Z0 = X^T/(col*row) (hi/lo) and Z0T = X/(col*row), LDS-tiled ----------------
__global__ __launch_bounds__(256) void ztinit_kernel(const u16* __restrict__ Xhi,
    const u16* __restrict__ Xlo, const float* __restrict__ scal,
    u16* __restrict__ Zhi, u16* __restrict__ Zlo, u16* __restrict__ ZThi, u16* __restrict__ ZTlo){
  int bh = blockIdx.x; int xr0 = blockIdx.y*64, xc0 = blockIdx.z*64;
  __shared__ float tb[64*66];
  float inv = 1.f/(scal[0]*scal[1]);
  int tid = threadIdx.x;
  size_t mo = (size_t)bh*65536;
  int row = tid>>2, cof = (tid&3)*16;
  #pragma unroll
  for (int s2=0;s2<2;s2++){
    sh8 hv = *(const sh8*)(Xhi + mo + (size_t)(xr0+row)*256 + xc0+cof+s2*8);
    sh8 lv = *(const sh8*)(Xlo + mo + (size_t)(xr0+row)*256 + xc0+cof+s2*8);
    #pragma unroll
    for (int j=0;j<8;j++) tb[row*66 + cof+s2*8+j] = (bf2f((u16)hv[j])+bf2f((u16)lv[j]))*inv;
  }
  __syncthreads();
  int lc = tid&63;
  #pragma unroll
  for (int i=0;i<16;i++){
    int lr = i*4 + (tid>>6);
    float v1 = tb[lr*66+lc];
    u16 h1 = f2bf(v1);
    ZThi[mo + (size_t)(xr0+lr)*256 + xc0+lc] = h1;
    ZTlo[mo + (size_t)(xr0+lr)*256 + xc0+lc] = f2bf(v1 - bf2f(h1));
    float v2 = tb[lc*66+lr];
    u16 h2 = f2bf(v2);
    Zhi[mo + (size_t)(xc0+lr)*256 + xr0+lc] = h2;
    Zlo[mo + (size_t)(xc0+lr)*256 + xr0+lc] = f2bf(v2 - bf2f(h2));
  }
}

// ---------------- batched 256^3 matmul body, 64x32 tiles, 3-term, dbuf staging.
// LO: read lo planes; OUTLO: write lo planes.
// val = k0*(A@B) + k1*E1[rc] + k2*E2[rc]; writes C and/or CT. ----------------
template<int LO, int OUTLO>
__device__ __forceinline__ void pinv_body(
    const u16* __restrict__ Ahi, const u16* __restrict__ Alo,
    const u16* __restrict__ Bthi, const u16* __restrict__ Btlo,
    const u16* __restrict__ E1hi, const u16* __restrict__ E1lo,
    const u16* __restrict__ E2hi, const u16* __restrict__ E2lo,
    u16* __restrict__ Chi, u16* __restrict__ Clo,
    u16* __restrict__ CThi, u16* __restrict__ CTlo,
    float k0, float k1, float k2, int bh, int r0, int col0,
    short* smem){
  size_t mo = (size_t)bh*65536;
  int tid=threadIdx.x, lane=tid&63, w=tid>>6;
  int srow = tid>>2, skof = (tid&3)*8;
  bool doB = tid < 128;
  const u16* pA  = Ahi + mo + (size_t)(r0+srow)*256 + skof;
  const u16* pAl = (LO? Alo : Ahi) + mo + (size_t)(r0+srow)*256 + skof;
  const u16* pB  = Bthi + mo + (size_t)(col0+(srow&31))*256 + skof;
  const u16* pBl = (LO? Btlo : Bthi) + mo + (size_t)(col0+(srow&31))*256 + skof;
  float e1v[2][4], e2v[2][4];
  if (E1hi){
    #pragma unroll
    for (int fc=0;fc<2;fc++){
      #pragma unroll
      for (int j=0;j<4;j++){
        int lr = w*16+((lane>>4)<<2)+j, lc = fc*16+(lane&15);
        size_t o = mo+(size_t)(r0+lr)*256+col0+lc;
        e1v[fc][j] = bf2f(E1hi[o]) + (LO ? bf2f(E1lo[o]) : 0.f);
      }
    }
  }
  if (E2hi){
    #pragma unroll
    for (int fc=0;fc<2;fc++){
      #pragma unroll
      for (int j=0;j<4;j++){
        int lr = w*16+((lane>>4)<<2)+j, lc = fc*16+(lane&15);
        size_t o = mo+(size_t)(r0+lr)*256+col0+lc;
        e2v[fc][j] = bf2f(E2hi[o]) + (LO ? bf2f(E2lo[o]) : 0.f);
      }
    }
  }
  sh8 ra = *(const sh8*)pA;
  sh8 ral{}, rbv{}, rbl{};
  if (LO) ral = *(const sh8*)pAl;
  if (doB){ rbv = *(const sh8*)pB; if (LO) rbl = *(const sh8*)pBl; }
  f4 acc[2];
  acc[0]=0; acc[1]=0;
  for (int kt=0;kt<8;kt++){
    short* Ah = smem + (kt&1)*7680;
    short* Al = Ah + 2560; short* Bh = Ah + 5120; short* Bl = Ah + 6400;
    *(sh8*)&Ah[srow*40+skof] = ra;
    if (LO) *(sh8*)&Al[srow*40+skof] = ral;
    if (doB){
      *(sh8*)&Bh[(srow&31)*40+skof] = rbv;
      if (LO) *(sh8*)&Bl[(srow&31)*40+skof] = rbl;
    }
    __syncthreads();
    if (kt<7){
      int o2 = (kt+1)*32;
      ra = *(const sh8*)(pA+o2);
      if (LO) ral = *(const sh8*)(pAl+o2);
      if (doB){ rbv = *(const sh8*)(pB+o2); if (LO) rbl = *(const sh8*)(pBl+o2); }
    }
    int aoff = (w*16+(lane&15))*40 + ((lane>>4)<<3);
    sh8 ah = *(const sh8*)&Ah[aoff];
    sh8 al8{};
    if (LO) al8 = *(const sh8*)&Al[aoff];
    sh8 bh8[2], bl8[2];
    #pragma unroll
    for (int fc=0;fc<2;fc++){
      int boff = (fc*16+(lane&15))*40 + ((lane>>4)<<3);
      bh8[fc] = *(const sh8*)&Bh[boff];
      if (LO) bl8[fc] = *(const sh8*)&Bl[boff];
    }
    #pragma unroll
    for (int fc=0;fc<2;fc++){
      acc[fc] = __builtin_amdgcn_mfma_f32_16x16x32_bf16(ah, bh8[fc], acc[fc], 0,0,0);
      if (LO){
        acc[fc] = __builtin_amdgcn_mfma_f32_16x16x32_bf16(ah, bl8[fc], acc[fc], 0,0,0);
        acc[fc] = __builtin_amdgcn_mfma_f32_16x16x32_bf16(al8, bh8[fc], acc[fc], 0,0,0);
      }
    }
  }
  __syncthreads();
  float* tb = (float*)smem;   // 64x36 f32 = 9216B
  #pragma unroll
  for (int fc=0;fc<2;fc++){
    #pragma unroll
    for (int j=0;j<4;j++){
      int lr = w*16+((lane>>4)<<2)+j, lc = fc*16+(lane&15);
      float val = k0*acc[fc][j];
      if (E1hi) val += k1*e1v[fc][j];
      if (E2hi) val += k2*e2v[fc][j];
      tb[lr*36+lc] = val;
    }
  }
  __syncthreads();
  if (Chi){
    int lr2 = tid>>2, cq=(tid&3)*8;
    sh8 hi8, lo8;
    #pragma unroll
    for (int jj=0;jj<8;jj++){
      float v1 = tb[lr2*36+cq+jj];
      u16 hb = f2bf(v1);
      hi8[jj] = (short)hb; lo8[jj] = (short)f2bf(v1-bf2f(hb));
    }
    *(sh8*)(Chi + mo + (size_t)(r0+lr2)*256 + col0+cq) = hi8;
    if (OUTLO) *(sh8*)(Clo + mo + (size_t)(r0+lr2)*256 + col0+cq) = lo8;
  }
  if (CThi){
    int lrT = tid>>3, cqT=(tid&7)*8;
    sh8 hi8, lo8;
    #pragma unroll
    for (int jj=0;jj<8;jj++){
      float v2 = tb[(cqT+jj)*36 + lrT];
      u16 hb = f2bf(v2);
      hi8[jj] = (short)hb; lo8[jj] = (short)f2bf(v2-bf2f(hb));
    }
    *(sh8*)(CThi + mo + (size_t)(col0+lrT)*256 + r0+cqT) = hi8;
    if (OUTLO) *(sh8*)(CTlo + mo + (size_t)(col0+lrT)*256 + r0+cqT) = lo8;
  }
}

template<int LO, int OUTLO>
__global__ __launch_bounds__(256) void pinv_mm(
    const u16* Ahi, const u16* Alo, const u16* Bthi, const u16* Btlo,
    const u16* E1hi, const u16* E1lo, const u16* E2hi, const u16* E2lo,
    u16* Chi, u16* Clo, u16* CThi, u16* CTlo,
    float k0, float k1, float k2){
  __shared__ __align__(16) short smem[2*7680];
  pinv_body<LO,OUTLO>(Ahi,Alo,Bthi,Btlo,E1hi,E1lo,E2hi,E2lo,Chi,Clo,CThi,CTlo,
            k0,k1,k2, blockIdx.z, blockIdx.x*64, blockIdx.y*32, smem);
}

// combined Z' and T1' update: both = 3.25*E1 - 0.25*(E1@T3); which = z>>5
template<int LO, int OUTLO>
__global__ __launch_bounds__(256) void pinv_zupd(
    const u16* Zhi, const u16* Zlo, u16* ZnHi, u16* ZnLo,
    const u16* T1hi, const u16* T1lo,
    u16* TnChi, u16* TnClo, u16* TnThi, u16* TnTlo,
    const u16* Bthi, const u16* Btlo){
  __shared__ __align__(16) short smem[2*7680];
  int which = blockIdx.z >> 5, bh = blockIdx.z & 31;
  const u16* Ah = which ? T1hi : Zhi;
  const u16* Al = which ? T1lo : Zlo;
  u16* Ch  = which ? TnChi : ZnHi;
  u16* Cl  = which ? TnClo : ZnLo;
  u16* CTh = which ? TnThi : (u16*)0;
  u16* CTl = which ? TnTlo : (u16*)0;
  pinv_body<LO,OUTLO>(Ah,Al,Bthi,Btlo, Ah,Al, (u16*)0,(u16*)0, Ch,Cl,CTh,CTl,
            -0.25f, 3.25f, 0.f, bh, blockIdx.x*64, blockIdx.y*32, smem);
}

// ---------------- flash attn3: partials of softmax(ql@k^T)@v with online softmax ----------------
__global__ __launch_bounds__(256) void flash_out3(const u16* __restrict__ qlall,
    const u16* __restrict__ kall, const u16* __restrict__ vall,
    float* __restrict__ part, float2* __restrict__ pms){
  int mt = blockIdx.x, ks = blockIdx.y, bh = blockIdx.z;
  const u16* QL = qlall + ((size_t)bh*256 + mt*128)*64;
  const u16* K  = kall + ((size_t)bh*4096 + (size_t)ks*512)*64;
  const u16* V  = vall + ((size_t)bh*4096 + (size_t)ks*512)*64;
  float* O = part + ((size_t)(bh*8+ks)*256 + (size_t)mt*128)*64;
  float2* MS = pms + (size_t)(bh*8+ks)*256 + mt*128;
  __shared__ __align__(16) short kls[64*72];
  __shared__ __align__(16) short vts[64*72];
  __shared__ __align__(16) short Pls[128*72];
  int tid=threadIdx.x, lane=tid&63, w=tid>>6;
  sh8 aq[2][2];
  #pragma unroll
  for (int fr=0;fr<2;fr++){
    #pragma unroll
    for (int kc=0;kc<2;kc++)
      aq[fr][kc] = *(const sh8*)(QL + (size_t)(w*32+fr*16+(lane&15))*64 + kc*32 + ((lane>>4)<<3));
  }
  f4 oacc[2][4];
  #pragma unroll
  for (int fr=0;fr<2;fr++){
    #pragma unroll
    for (int fc=0;fc<4;fc++) oacc[fr][fc]=0;
  }
  float mrun[2][4], srun[2][4];
  #pragma unroll
  for (int fr=0;fr<2;fr++){
    #pragma unroll
    for (int j=0;j<4;j++){ mrun[fr][j]=-1e30f; srun[fr][j]=0.f; }
  }
  for (int kt=0;kt<8;kt++){
    __syncthreads();
    #pragma unroll
    for (int i=0;i<2;i++){
      int c=i*256+tid, row=c>>3, kg=c&7;
      *(sh8*)&kls[row*72+kg*8] = *(const sh8*)(K + (size_t)(kt*64+row)*64 + kg*8);
    }
    #pragma unroll
    for (int i=0;i<16;i++){
      int c=i*256+tid, d=c&63, nl=c>>6;
      vts[d*72+nl] = (short)V[(size_t)(kt*64+nl)*64 + d];
    }
    __syncthreads();
    f4 sacc[2][4];
    #pragma unroll
    for (int fr=0;fr<2;fr++){
      #pragma unroll
      for (int fc=0;fc<4;fc++) sacc[fr][fc]=0;
    }
    #pragma unroll
    for (int kc=0;kc<2;kc++){
      sh8 bk[4];
      #pragma unroll
      for (int fc=0;fc<4;fc++) bk[fc] = *(const sh8*)&kls[(fc*16+(lane&15))*72 + kc*32 + ((lane>>4)<<3)];
      #pragma unroll
      for (int fr=0;fr<2;fr++){
        #pragma unroll
        for (int fc=0;fc<4;fc++)
          sacc[fr][fc] = __builtin_amdgcn_mfma_f32_16x16x32_bf16(aq[fr][kc], bk[fc], sacc[fr][fc], 0,0,0);
      }
    }
    #pragma unroll
    for (int fr=0;fr<2;fr++){
      #pragma unroll
      for (int j=0;j<4;j++){
        float mt_ = fmaxf(fmaxf(sacc[fr][0][j],sacc[fr][1][j]), fmaxf(sacc[fr][2][j],sacc[fr][3][j]));
        #pragma unroll
        for (int o=1;o<16;o<<=1) mt_ = fmaxf(mt_, __shfl_xor(mt_,o));
        float mnew = fmaxf(mrun[fr][j], mt_);
        float scale = __expf(mrun[fr][j]-mnew);
        float e0 = __expf(sacc[fr][0][j]-mnew);
        float e1 = __expf(sacc[fr][1][j]-mnew);
        float e2 = __expf(sacc[fr][2][j]-mnew);
        float e3 = __expf(sacc[fr][3][j]-mnew);
        sacc[fr][0][j]=e0; sacc[fr][1][j]=e1; sacc[fr][2][j]=e2; sacc[fr][3][j]=e3;
        float sum = (e0+e1)+(e2+e3);
        #pragma unroll
        for (int o=1;o<16;o<<=1) sum += __shfl_xor(sum,o);
        srun[fr][j] = srun[fr][j]*scale + sum;
        mrun[fr][j] = mnew;
        #pragma unroll
        for (int fc=0;fc<4;fc++) oacc[fr][fc][j] *= scale;
      }
    }
    #pragma unroll
    for (int fr=0;fr<2;fr++){
      #pragma unroll
      for (int fc=0;fc<4;fc++){
        #pragma unroll
        for (int j=0;j<4;j++)
          Pls[(w*32+fr*16+((lane>>4)<<2)+j)*72 + fc*16+(lane&15)] = (short)f2bf(sacc[fr][fc][j]);
      }
    }
    #pragma unroll
    for (int kc=0;kc<2;kc++){
      sh8 pa[2], bv[4];
      #pragma unroll
      for (int fr=0;fr<2;fr++) pa[fr] = *(const sh8*)&Pls[(w*32+fr*16+(lane&15))*72 + kc*32 + ((lane>>4)<<3)];
      #pragma unroll
      for (int fc=0;fc<4;fc++) bv[fc] = *(const sh8*)&vts[(fc*16+(lane&15))*72 + kc*32 + ((lane>>4)<<3)];
      #pragma unroll
      for (int fr=0;fr<2;fr++){
        #pragma unroll
        for (int fc=0;fc<4;fc++)
          oacc[fr][fc] = __builtin_amdgcn_mfma_f32_16x16x32_bf16(pa[fr], bv[fc], oacc[fr][fc], 0,0,0);
      }
    }
  }
  #pragma unroll
  for (int fr=0;fr<2;fr++){
    #pragma unroll
    for (int fc=0;fc<4;fc++){
      #pragma unroll
      for (int j=0;j<4;j++)
        O[(size_t)(w*32+fr*16+((lane>>4)<<2)+j)*64 + fc*16+(lane&15)] = oacc[fr][fc][j];
    }
  }
  if ((lane&15)==0){
    #pragma unroll
    for (int fr=0;fr<2;fr++){
      #pragma unroll
      for (int j=0;j<4;j++)
        MS[w*32+fr*16+((lane>>4)<<2)+j] = make_float2(mrun[fr][j], srun[fr][j]);
    }
  }
}

// ---------------- flash merge of 8 K-split partials ----------------
__global__ __launch_bounds__(256) void reduce_o3(const float* __restrict__ part,
    const float2* __restrict__ pms, float* __restrict__ o3){
  int idx = blockIdx.x*256+threadIdx.x;
  int d = idx&63, row = (idx>>6)&255, bh = idx>>14;
  float2 ms[8];
  float M = -1e30f;
  #pragma unroll
  for (int ks=0;ks<8;ks++){
    ms[ks] = pms[(size_t)(bh*8+ks)*256 + row];
    M = fmaxf(M, ms[ks].x);
  }
  float S=0.f, acc=0.f;
  #pragma unroll
  for (int ks=0;ks<8;ks++){
    float e = __expf(ms[ks].x - M);
    S += e*ms[ks].y;
    acc += e*part[((size_t)(bh*8+ks)*256 + row)*64 + d];
  }
  o3[idx] = acc/S;
}

// ---------------- Wt[d][m] = (z @ out3)[m][d] bf16, z in hi/lo ----------------
__global__ __launch_bounds__(256) void wt_kernel(const u16* __restrict__ Zhi,
    const u16* __restrict__ Zlo, const float* __restrict__ o3, u16* __restrict__ Wt){
  int bh = blockIdx.x; int m = blockIdx.y*4 + (threadIdx.x>>6); int d = threadIdx.x&63;
  const u16* zh = Zhi + ((size_t)bh*256 + m)*256;
  const u16* zl = Zlo + ((size_t)bh*256 + m)*256;
  const float* op = o3 + (size_t)bh*256*64 + d;
  float accv = 0;
  for (int kk=0;kk<256;kk++) accv += (bf2f(zh[kk])+bf2f(zl[kk]))*op[kk*64];
  Wt[((size_t)bh*64 + d)*256 + m] = f2bf(accv);
}

// ---------------- fused out1 = softmax_row(q @ kl^T) @ W, 64 q-rows/block, bf16 out ----------------
__global__ __launch_bounds__(256) void fused_out1(const u16* __restrict__ q,
    const u16* __restrict__ klall, const u16* __restrict__ Wtall, u16* __restrict__ Oall){
  int rb = blockIdx.x, bh = blockIdx.y;
  __shared__ __align__(16) short sm[18432];   // Bs 256x72 ; then P (64x268); then out bounce
  short* Bs = sm; short* P = sm;
  int tid=threadIdx.x, lane=tid&63, w=tid>>6;
  const u16* qb  = q + ((size_t)bh*4096 + (size_t)rb*64)*64;
  const u16* klb = klall + (size_t)bh*256*64;
  const u16* Wt  = Wtall + (size_t)bh*64*256;
  #pragma unroll
  for (int i=0;i<8;i++){
    int c = i*256+tid, row = c>>3, kg = c&7;
    *(sh8*)&Bs[row*72+kg*8] = *(const sh8*)(klb + row*64 + kg*8);
  }
  const u16* qrow = qb + (size_t)(w*16+(lane&15))*64 + ((lane>>4)<<3);
  sh8 a0 = *(const sh8*)(qrow);
  sh8 a1 = *(const sh8*)(qrow + 32);
  __syncthreads();
  // S = q @ kl^T : 16 rows/wave x 256 cols
  f4 acc[16];
  #pragma unroll
  for (int fc=0;fc<16;fc++){
    sh8 b0 = *(const sh8*)&Bs[(fc*16+(lane&15))*72 + ((lane>>4)<<3)];
    sh8 b1 = *(const sh8*)&Bs[(fc*16+(lane&15))*72 + 32 + ((lane>>4)<<3)];
    acc[fc]=0;
    acc[fc] = __builtin_amdgcn_mfma_f32_16x16x32_bf16(a0, b0, acc[fc], 0,0,0);
    acc[fc] = __builtin_amdgcn_mfma_f32_16x16x32_bf16(a1, b1, acc[fc], 0,0,0);
  }
  // issue first Wt prefetch EARLY: latency hides under softmax + P-write (T14 pattern)
  sh8 bqA[4], bqB[4];
  #pragma unroll
  for (int fc2=0;fc2<4;fc2++){
    int d = fc2*16 + (lane&15);
    bqA[fc2] = *(const sh8*)(Wt + (size_t)d*256 + ((lane>>4))*8);
  }
  // in-register row softmax, tree-reduced
  float inv_[4];
  #pragma unroll
  for (int j=0;j<4;j++){
    float m0 = fmaxf(fmaxf(acc[0][j],acc[1][j]), fmaxf(acc[2][j],acc[3][j]));
    float m1 = fmaxf(fmaxf(acc[4][j],acc[5][j]), fmaxf(acc[6][j],acc[7][j]));
    float m2 = fmaxf(fmaxf(acc[8][j],acc[9][j]), fmaxf(acc[10][j],acc[11][j]));
    float m3 = fmaxf(fmaxf(acc[12][j],acc[13][j]), fmaxf(acc[14][j],acc[15][j]));
    float mx = fmaxf(fmaxf(m0,m1), fmaxf(m2,m3));
    #pragma unroll
    for (int o=1;o<16;o<<=1) mx = fmaxf(mx, __shfl_xor(mx,o));
    float e[16];
    #pragma unroll
    for (int fc=0;fc<16;fc++){ e[fc]=__expf(acc[fc][j]-mx); acc[fc][j]=e[fc]; }
    float s = (((e[0]+e[1])+(e[2]+e[3])) + ((e[4]+e[5])+(e[6]+e[7])))
            + (((e[8]+e[9])+(e[10]+e[11])) + ((e[12]+e[13])+(e[14]+e[15])));
    #pragma unroll
    for (int o=1;o<16;o<<=1) s += __shfl_xor(s,o);
    inv_[j] = 1.f/s;
  }
  __syncthreads();
  #pragma unroll
  for (int fc=0;fc<16;fc++){
    #pragma unroll
    for (int j=0;j<4;j++){
      int row = w*16 + ((lane>>4)<<2) + j, col = fc*16 + (lane&15);
      P[row*268 + col] = (short)f2bf(acc[fc][j]*inv_[j]);
    }
  }
  __syncthreads();
  // out = P @ W, K=256; Wt b-fragments software-pipelined 2-deep from global
  f4 acc2[4];
  #pragma unroll
  for (int fc2=0;fc2<4;fc2++) acc2[fc2]=0;
  #pragma unroll
  for (int kp=0;kp<4;kp++){
    int kc0 = kp*2, kc1 = kp*2+1;
    #pragma unroll
    for (int fc2=0;fc2<4;fc2++){
      int d = fc2*16 + (lane&15);
      bqB[fc2] = *(const sh8*)(Wt + (size_t)d*256 + (kc1*4+(lane>>4))*8);
    }
    sh8 a = *(const sh8*)&P[(w*16+(lane&15))*268 + kc0*32 + ((lane>>4)<<3)];
    #pragma unroll
    for (int fc2=0;fc2<4;fc2++)
      acc2[fc2] = __builtin_amdgcn_mfma_f32_16x16x32_bf16(a, bqA[fc2], acc2[fc2], 0,0,0);
    if (kp<3){
      #pragma unroll
      for (int fc2=0;fc2<4;fc2++){
        int d = fc2*16 + (lane&15);
        bqA[fc2] = *(const sh8*)(Wt + (size_t)d*256 + ((kc1+1)*4+(lane>>4))*8);
      }
    }
    sh8 a2 = *(const sh8*)&P[(w*16+(lane&15))*268 + kc1*32 + ((lane>>4)<<3)];
    #pragma unroll
    for (int fc2=0;fc2<4;fc2++)
      acc2[fc2] = __builtin_amdgcn_mfma_f32_16x16x32_bf16(a2, bqB[fc2], acc2[fc2], 0,0,0);
  }
  // bounce to LDS, emit coalesced 16B bf16 stores
  __syncthreads();
  u16* otb = (u16*)sm;
  #pragma unroll
  for (int fc2=0;fc2<4;fc2++){
    #pragma unroll
    for (int j=0;j<4;j++)
      otb[(w*16+((lane>>4)<<2)+j)*72 + fc2*16+(lane&15)] = f2bf(acc2[fc2][j]);
  }
  __syncthreads();
  u16* O = Oall + ((size_t)bh*4096 + (size_t)rb*64)*64;
  #pragma unroll
  for (int i=0;i<2;i++){
    int ch = i*256+tid; int lr = ch>>3, cq = (ch&7)*8;
    sh8 ov = *(sh8*)&otb[lr*72+cq];
    *(sh8*)(O + (size_t)lr*64 + cq) = ov;
  }
}

// ---------------- combine: register-window depthwise conv + residual add (bf16 in) ----------------
__global__ __launch_bounds__(256) void combine_kernel(const u16* __restrict__ out1,
    const u16* __restrict__ v, const float* __restrict__ wres, u16* __restrict__ oc){
  int bh = blockIdx.x; int hh = bh&7, bb = bh>>3;
  int n0 = blockIdx.y*64;
  int tid = threadIdx.x, d = tid&63, sub = tid>>6;
  int nbase = n0 + sub*16;
  const u16* vb = v + ((size_t)bh*4096)*64 + d;
  float w_[33];
  #pragma unroll
  for (int j=0;j<33;j++) w_[j] = wres[hh*33+j];
  float vv[48];
  #pragma unroll
  for (int i=0;i<48;i++){
    int nn = nbase + i - 16;
    vv[i] = (nn>=0 && nn<4096) ? bf2f(vb[(size_t)nn*64]) : 0.f;
  }
  #pragma unroll
  for (int r=0;r<16;r++){
    int n = nbase + r;
    float acc = bf2f(out1[(((size_t)bh*4096)+n)*64 + d]);
    #pragma unroll
    for (int j=0;j<33;j++) acc += w_[j]*vv[r+j];
    oc[((size_t)(bb*4096+n))*512 + hh*64 + d] = f2bf(acc);
  }
}

// ---------------- final: out = x + ocomb @ w_out + b_out ----------------
__global__ __launch_bounds__(256) void gemm_final(const u16* __restrict__ A,
    const u16* __restrict__ Bt, const float* __restrict__ x, const float* __restrict__ bo,
    float* __restrict__ out){
  __shared__ short As[128*72], Bs[128*72];
  int r0 = blockIdx.x*128, c0 = blockIdx.y*128;
  int tid = threadIdx.x, lane = tid&63, w = tid>>6;
  int wr = w>>1, wc = w&1;
  f4 acc[4][4];
  #pragma unroll
  for (int i=0;i<4;i++){
    #pragma unroll
    for (int j=0;j<4;j++) acc[i][j]=0;
  }
  for (int kt=0;kt<8;kt++){
    __syncthreads();
    #pragma unroll
    for (int i=0;i<4;i++){
      int c = i*256+tid, row = c>>3, kg = c&7;
      *(sh8*)&As[row*72+kg*8] = *(const sh8*)(A  + (size_t)(r0+row)*512 + kt*64 + kg*8);
      *(sh8*)&Bs[row*72+kg*8] = *(const sh8*)(Bt + (size_t)(c0+row)*512 + kt*64 + kg*8);
    }
    __syncthreads();
    #pragma unroll
    for (int kc=0;kc<2;kc++){
      sh8 a[4], bq[4];
      #pragma unroll
      for (int fr=0;fr<4;fr++) a[fr]  = *(const sh8*)&As[(wr*64+fr*16+(lane&15))*72 + kc*32 + ((lane>>4)<<3)];
      #pragma unroll
      for (int fc=0;fc<4;fc++) bq[fc] = *(const sh8*)&Bs[(wc*64+fc*16+(lane&15))*72 + kc*32 + ((lane>>4)<<3)];
      #pragma unroll
      for (int fr=0;fr<4;fr++){
        #pragma unroll
        for (int fc=0;fc<4;fc++)
          acc[fr][fc] = __builtin_amdgcn_mfma_f32_16x16x32_bf16(a[fr], bq[fc], acc[fr][fc], 0,0,0);
      }
    }
  }
  #pragma unroll
  for (int fr=0;fr<4;fr++){
    #pragma unroll
    for (int fc=0;fc<4;fc++){
      #pragma unroll
      for (int j=0;j<4;j++){
        int r = r0 + wr*64 + fr*16 + ((lane>>4)<<2) + j;
        int c = c0 + wc*64 + fc*16 + (lane&15);
        out[(size_t)r*512+c] = x[(size_t)r*512+c] + acc[fr][fc][j] + bo[c];
      }
    }
  }
}

extern "C" void kernel_launch(void* const* d_in, const int* in_sizes, int n_in,
                              void* d_out, int out_size, void* d_ws, size_t ws_size,
                              hipStream_t stream){
  const float* x    = (const float*)d_in[0];
  const float* lnw  = (const float*)d_in[1];
  const float* lnb  = (const float*)d_in[2];
  const float* wqkv = (const float*)d_in[3];
  const float* wout = (const float*)d_in[4];
  const float* bout = (const float*)d_in[5];
  const float* wres = (const float*)d_in[6];
  float* out = (float*)d_out;

  char* ws = (char*)d_ws;
  size_t off = 0;
  auto alloc = [&](size_t bytes)->void*{ void* p = ws + off; off += (bytes + 255) & ~(size_t)255; return p; };
  u16* h      = (u16*)alloc((size_t)NT_*512*2);          // aliased later as oc
  u16* wqkvT  = (u16*)alloc((size_t)1536*512*2);
  u16* woutT  = (u16*)alloc((size_t)512*512*2);
  u16* k      = (u16*)alloc((size_t)BH_*4096*64*2);
  u16* v      = (u16*)alloc((size_t)BH_*4096*64*2);
  u16* q      = (u16*)alloc((size_t)BH_*4096*64*2);
  float* part = (float*)alloc((size_t)BH_*8*256*64*4);   // ZT tmp aliases here during pinv
  float2* pms = (float2*)alloc((size_t)BH_*8*256*8);
  u16* ql     = (u16*)alloc((size_t)BH_*256*64*2);
  u16* kl     = (u16*)alloc((size_t)BH_*256*64*2);
  u16* ZaChi  = (u16*)alloc((size_t)BH_*65536*2);        // final z lands here
  u16* ZaClo  = (u16*)alloc((size_t)BH_*65536*2);
  u16* ZbChi  = (u16*)alloc((size_t)BH_*65536*2);
  u16* ZbClo  = (u16*)alloc((size_t)BH_*65536*2);
  u16* scratch = (u16*)alloc((size_t)BH_*65536*2*16);    // 64 MiB pinv scratch; out1 aliases
  float* o3   = (float*)alloc((size_t)BH_*256*64*4);
  u16* Wt     = (u16*)alloc((size_t)BH_*64*256*2);
  float* scal = (float*)alloc(256);
  u16* out1   = scratch;        // scratch dead after pinv+wt
  u16* oc     = h;              // h dead after qkv gemm

  const size_t C1 = (size_t)BH_*65536;
  u16* base = scratch;
  u16* Xhi   = base + 0*C1;  u16* Xlo   = base + 1*C1;
  u16* T1aCh = base + 2*C1;  u16* T1aCl = base + 3*C1;
  u16* T1aTh = base + 4*C1;  u16* T1aTl = base + 5*C1;
  u16* T1bCh = base + 6*C1;  u16* T1bCl = base + 7*C1;
  u16* T1bTh = base + 8*C1;  u16* T1bTl = base + 9*C1;
  u16* SCh   = base +10*C1;  u16* SCl   = base +11*C1;   // Z0T aliases here (dead after T1_0)
  u16* STh   = base +12*C1;  u16* STl   = base +13*C1;
  u16* T3h   = base +14*C1;  u16* T3l   = base +15*C1;
  u16* Z0Th  = SCh;          u16* Z0Tl  = SCl;
  u16* ZTth  = (u16*)part;   u16* ZTtl  = ZTth + C1;     // Z^T tmp for refresh (part dead in pinv)

  prep_kernel<<<NT_ + (512*1536+512*512+255)/256, 256, 0, stream>>>(
      x, lnw, lnb, h, wqkv, wqkvT, wout, woutT);
  gemm_qkv<<<dim3(128,12,1), 256, 0, stream>>>(h, wqkvT, q, k, v);
  landmark_kernel<<<dim3(32,256,1), 64, 0, stream>>>(q, k, ql, kl);
  attn2_kernel<<<dim3(32,16,1), 256, 0, stream>>>(ql, kl, Xhi, Xlo);
  hipMemsetAsync(scal, 0, 8, stream);
  colrow_kernel<<<32, 256, 0, stream>>>(Xhi, Xlo, scal);
  ztinit_kernel<<<dim3(32,4,4), 256, 0, stream>>>(Xhi, Xlo, scal, ZaChi, ZaClo, Z0Th, Z0Tl);

  u16* nul = (u16*)0;
  // T1_0 = X @ Z0  (hi-only outputs: lo planes unread before the it==4 refresh)
  pinv_mm<1,0><<<dim3(4,8,32),256,0,stream>>>(Xhi,Xlo, Z0Th,Z0Tl, nul,nul,nul,nul,
      T1aCh,T1aCl, T1aTh,T1aTl, 1.f,0.f,0.f);
  u16 *TcCh=T1aCh,*TcCl=T1aCl,*TcTh=T1aTh,*TcTl=T1aTl;
  u16 *TnCh=T1bCh,*TnCl=T1bCl,*TnTh=T1bTh,*TnTl=T1bTl;
  u16 *Zch=ZaChi,*Zcl=ZaClo, *Znh=ZbChi,*Znl=ZbClo;
  for (int it=0; it<6; it++){
    if (it==4){
      // refresh true residual: T1 = X @ Z  (Z^T captured at it==3)
      pinv_mm<1,1><<<dim3(4,8,32),256,0,stream>>>(Xhi,Xlo, ZTth,ZTtl, nul,nul,nul,nul,
          TnCh,TnCl, TnTh,TnTl, 1.f,0.f,0.f);
      u16* t;
      t=TcCh;TcCh=TnCh;TnCh=t; t=TcCl;TcCl=TnCl;TnCl=t;
      t=TcTh;TcTh=TnTh;TnTh=t; t=TcTl;TcTl=TnTl;TnTl=t;
    }
    if (it<4){
      pinv_mm<0,0><<<dim3(4,8,32),256,0,stream>>>(TcCh,TcCl, TcTh,TcTl, nul,nul,nul,nul,
          SCh,SCl, STh,STl, 1.f,0.f,0.f);
      pinv_mm<0,0><<<dim3(4,8,32),256,0,stream>>>(TcCh,TcCl, STh,STl, TcCh,TcCl, SCh,SCl,
          nul,nul, T3h,T3l, 1.f,15.f,-7.f);
    } else {
      pinv_mm<1,1><<<dim3(4,8,32),256,0,stream>>>(TcCh,TcCl, TcTh,TcTl, nul,nul,nul,nul,
          SCh,SCl, STh,STl, 1.f,0.f,0.f);
      pinv_mm<1,1><<<dim3(4,8,32),256,0,stream>>>(TcCh,TcCl, STh,STl, TcCh,TcCl, SCh,SCl,
          nul,nul, T3h,T3l, 1.f,15.f,-7.f);
    }
    if (it<3){
      pinv_zupd<0,0><<<dim3(4,8,64),256,0,stream>>>(Zch,Zcl, Znh,Znl,
          TcCh,TcCl, TnCh,TnCl, TnTh,TnTl, T3h,T3l);
      u16* t;
      t=Zch;Zch=Znh;Znh=t; t=Zcl;Zcl=Znl;Znl=t;
      t=TcCh;TcCh=TnCh;TnCh=t; t=TcCl;TcCl=TnCl;TnCl=t;
      t=TcTh;TcTh=TnTh;TnTh=t; t=TcTl;TcTl=TnTl;TnTl=t;
    } else if (it==3){
      // Z' only (T1' of it3 is replaced by the it4 refresh); capture Z'^T for refresh
      pinv_mm<0,1><<<dim3(4,8,32),256,0,stream>>>(Zch,Zcl, T3h,T3l, Zch,Zcl, nul,nul,
          Znh,Znl, ZTth,ZTtl, -0.25f,3.25f,0.f);
      u16* t;
      t=Zch;Zch=Znh;Znh=t; t=Zcl;Zcl=Znl;Znl=t;
    } else if (it==4){
      pinv_zupd<1,1><<<dim3(4,8,64),256,0,stream>>>(Zch,Zcl, Znh,Znl,
          TcCh,TcCl, TnCh,TnCl, TnTh,TnTl, T3h,T3l);
      u16* t;
      t=Zch;Zch=Znh;Znh=t; t=Zcl;Zcl=Znl;Znl=t;
      t=TcCh;TcCh=TnCh;TnCh=t; t=TcCl;TcCl=TnCl;TnCl=t;
      t=TcTh;TcTh=TnTh;TnTh=t; t=TcTl;TcTl=TnTl;TnTl=t;
    } else {
      pinv_mm<1,1><<<dim3(4,8,32),256,0,stream>>>(Zch,Zcl, T3h,T3l, Zch,Zcl, nul,nul,
          Znh,Znl, nul,nul, -0.25f,3.25f,0.f);
    }
  }
  // Z swaps at it0..4 (5 swaps): final write lands in ZaChi/ZaClo

  flash_out3<<<dim3(2,8,32),256,0,stream>>>(ql, k, v, part, pms);
  reduce_o3<<<2048, 256, 0, stream>>>(part, pms, o3);
  wt_kernel<<<dim3(32,64,1),256,0,stream>>>(ZaChi, ZaClo, o3, Wt);
  fused_out1<<<dim3(64,32,1),256,0,stream>>>(q, kl, Wt, out1);
  combine_kernel<<<dim3(32,64,1),256,0,stream>>>(out1, v, wres, oc);
  gemm_final<<<dim3(128,4,1),256,0,stream>>>(oc, woutT, x, bout, out);
}